// Round 2
// baseline (8201.922 us; speedup 1.0000x reference)
//
#include <hip/hip_runtime.h>

#define DEV static __device__ __forceinline__

// LayerNorm over 3 elements: (x-m)/sqrt(v+eps)*g + b   (eps inside sqrt, biased var)
DEV void ln3(float& a, float& b, float& c, const float* g, const float* bt) {
  float m = (a + b + c) * (1.0f / 3.0f);
  float d0 = a - m, d1 = b - m, d2 = c - m;
  float v = (d0 * d0 + d1 * d1 + d2 * d2) * (1.0f / 3.0f);
  float rs = rsqrtf(v + 1e-5f);
  a = fmaf(d0 * rs, g[0], bt[0]);
  b = fmaf(d1 * rs, g[1], bt[1]);
  c = fmaf(d2 * rs, g[2], bt[2]);
}

// ---------------------------------------------------------------------------
// Prepack fp32 weights into ws layouts:
//   FW[l][j] = float4{w1[j][0],w1[j][1],w1[j][2], b1[j]}   l=0..23 (12 enc, 12 dec)
//   SW[l][j] = float4{w2[0][j],w2[1][j],w2[2][j], 0}
//   SMALL[l][128]: attn/LN scalars (layout documented inline)
//   GLOB[16]: enc_norm g,b ; dec_norm g,b
// ---------------------------------------------------------------------------
__global__ void __launch_bounds__(256) prepack_kernel(
    const float* ea_w, const float* ea_b, const float* ea_ow, const float* ea_ob,
    const float* el1g, const float* el1b, const float* el2g, const float* el2b,
    const float* ef1w, const float* ef1b, const float* ef2w, const float* ef2b,
    const float* eng, const float* enb,
    const float* dsw, const float* dsb, const float* dsow, const float* dsob,
    const float* dcw, const float* dcb, const float* dcow, const float* dcob,
    const float* dl1g, const float* dl1b, const float* dl2g, const float* dl2b,
    const float* dl3g, const float* dl3b,
    const float* df1w, const float* df1b, const float* df2w, const float* df2b,
    const float* dng, const float* dnb,
    float* ws) {
  const int l = blockIdx.x, tid = threadIdx.x;
  const bool enc = l < 12;
  const int li = enc ? l : l - 12;
  const float* f1w = (enc ? ef1w : df1w) + li * 2048 * 3;
  const float* f1b = (enc ? ef1b : df1b) + li * 2048;
  const float* f2w = (enc ? ef2w : df2w) + li * 3 * 2048;
  float* FW = ws + (size_t)l * 8192;
  float* SW = ws + 24 * 8192 + (size_t)l * 8192;
  for (int j = tid; j < 2048; j += 256) {
    FW[j * 4 + 0] = f1w[j * 3 + 0];
    FW[j * 4 + 1] = f1w[j * 3 + 1];
    FW[j * 4 + 2] = f1w[j * 3 + 2];
    FW[j * 4 + 3] = f1b[j];
    SW[j * 4 + 0] = f2w[j];
    SW[j * 4 + 1] = f2w[2048 + j];
    SW[j * 4 + 2] = f2w[4096 + j];
    SW[j * 4 + 3] = 0.0f;
  }
  float* S = ws + 48 * 8192 + l * 128;
  if (tid == 0) {
    // 0-26 qkv W (rows q0..2,k0..2,v0..2) | 27-35 qkv b | 36-44 ow | 45-47 ob
    // 48-53 ln1 g,b | 54-59 ln2 g,b | 60-62 ffn b2
    const float* aw = (enc ? ea_w : dsw) + li * 27;
    const float* ab = (enc ? ea_b : dsb) + li * 9;
    const float* aow = (enc ? ea_ow : dsow) + li * 9;
    const float* aob = (enc ? ea_ob : dsob) + li * 3;
    for (int i = 0; i < 27; ++i) S[i] = aw[i];
    for (int i = 0; i < 9; ++i) S[27 + i] = ab[i];
    for (int i = 0; i < 9; ++i) S[36 + i] = aow[i];
    for (int i = 0; i < 3; ++i) S[45 + i] = aob[i];
    const float* p;
    p = (enc ? el1g : dl1g) + li * 3; for (int i = 0; i < 3; ++i) S[48 + i] = p[i];
    p = (enc ? el1b : dl1b) + li * 3; for (int i = 0; i < 3; ++i) S[51 + i] = p[i];
    p = (enc ? el2g : dl2g) + li * 3; for (int i = 0; i < 3; ++i) S[54 + i] = p[i];
    p = (enc ? el2b : dl2b) + li * 3; for (int i = 0; i < 3; ++i) S[57 + i] = p[i];
    p = (enc ? ef2b : df2b) + li * 3; for (int i = 0; i < 3; ++i) S[60 + i] = p[i];
    if (!enc) {
      // 64-72 cross qW | 73-75 cross qb | 76-84 cross ow | 85-87 cross ob
      // 88-93 ln3 g,b | 94-102 cross kW | 103-105 kb | 106-114 vW | 115-117 vb
      const float* cw = dcw + li * 27;
      for (int i = 0; i < 9; ++i) {
        S[64 + i] = cw[i];
        S[94 + i] = cw[9 + i];
        S[106 + i] = cw[18 + i];
      }
      const float* cb = dcb + li * 9;
      for (int i = 0; i < 3; ++i) {
        S[73 + i] = cb[i];
        S[103 + i] = cb[3 + i];
        S[115 + i] = cb[6 + i];
      }
      for (int i = 0; i < 9; ++i) S[76 + i] = dcow[li * 9 + i];
      for (int i = 0; i < 3; ++i) S[85 + i] = dcob[li * 3 + i];
      p = dl3g + li * 3; for (int i = 0; i < 3; ++i) S[88 + i] = p[i];
      p = dl3b + li * 3; for (int i = 0; i < 3; ++i) S[91 + i] = p[i];
    }
  }
  if (l == 0 && tid == 1) {
    float* G = ws + 48 * 8192 + 24 * 128;
    for (int i = 0; i < 3; ++i) {
      G[i] = eng[i]; G[3 + i] = enb[i];
      G[6 + i] = dng[i]; G[9 + i] = dnb[i];
    }
  }
}

// ---------------------------------------------------------------------------
// One transformer layer (encoder if ckv==nullptr, else decoder with cross-attn).
// R = number of virtual rows; row R-1 has key-multiplicity (64-t) when t>0.
// Phases: A qkv(wave0) | B1 self partials(w0-11) | C1 combine+LN1(+crossQ)(w0)
//         [B2 cross partials | C2 combine+LN2] | FFN(all waves, 4 rows/wave)
// ---------------------------------------------------------------------------
DEV void run_layer(const float* sm, const float* fw, const float* sw,
                   float (*h)[5], float (*qs)[5], float (*kvw)[9],
                   float (*part)[25], const float (*ckv)[8],
                   int wave, int lane, int R, int t) {
  // Phase A: q,k,v projections, one row per lane (wave 0)
  if (wave == 0 && lane < R) {
    const int r = lane;
    float x0 = h[r][0], x1 = h[r][1], x2 = h[r][2];
    float q0 = fmaf(sm[0], x0, fmaf(sm[1], x1, fmaf(sm[2], x2, sm[27])));
    float q1 = fmaf(sm[3], x0, fmaf(sm[4], x1, fmaf(sm[5], x2, sm[28])));
    float q2 = fmaf(sm[6], x0, fmaf(sm[7], x1, fmaf(sm[8], x2, sm[29])));
    float k0 = fmaf(sm[9], x0, fmaf(sm[10], x1, fmaf(sm[11], x2, sm[30])));
    float k1 = fmaf(sm[12], x0, fmaf(sm[13], x1, fmaf(sm[14], x2, sm[31])));
    float k2 = fmaf(sm[15], x0, fmaf(sm[16], x1, fmaf(sm[17], x2, sm[32])));
    float v0 = fmaf(sm[18], x0, fmaf(sm[19], x1, fmaf(sm[20], x2, sm[33])));
    float v1 = fmaf(sm[21], x0, fmaf(sm[22], x1, fmaf(sm[23], x2, sm[34])));
    float v2 = fmaf(sm[24], x0, fmaf(sm[25], x1, fmaf(sm[26], x2, sm[35])));
    qs[r][0] = q0; qs[r][1] = q1; qs[r][2] = q2;
    kvw[r][0] = k0; kvw[r][1] = k1; kvw[r][2] = k2;
    kvw[r][3] = v0; kvw[r][4] = v1; kvw[r][5] = v2;
    kvw[r][6] = (t > 0 && r == R - 1) ? (float)(64 - t) : 1.0f;
  }
  __syncthreads();
  // Phase B1: self-attn partial softmax sums. wave = head + 3*chunk
  if (wave < 12 && lane < R) {
    const int hd = wave % 3, c = wave / 3;
    const int p0 = c * 16, p1 = min(p0 + 16, R);
    float q = qs[lane][hd] * 1.44269504f;  // fold log2(e)
    float den = 0.f, num = 0.f;
    for (int p = p0; p < p1; ++p) {
      float e = exp2f(q * kvw[p][hd]) * kvw[p][6];
      den += e;
      num = fmaf(e, kvw[p][3 + hd], num);
    }
    part[lane][wave * 2 + 0] = den;
    part[lane][wave * 2 + 1] = num;
  }
  __syncthreads();
  // Phase C1: combine heads, out-proj, residual, LN1 (+ cross-q projection)
  if (wave == 0 && lane < R) {
    const int r = lane;
    float oh[3];
#pragma unroll
    for (int hd = 0; hd < 3; ++hd) {
      float den = part[r][hd * 2] + part[r][hd * 2 + 6] + part[r][hd * 2 + 12] + part[r][hd * 2 + 18];
      float num = part[r][hd * 2 + 1] + part[r][hd * 2 + 7] + part[r][hd * 2 + 13] + part[r][hd * 2 + 19];
      oh[hd] = __fdividef(num, den);
    }
    float a0 = fmaf(sm[36], oh[0], fmaf(sm[37], oh[1], fmaf(sm[38], oh[2], sm[45]))) + h[r][0];
    float a1 = fmaf(sm[39], oh[0], fmaf(sm[40], oh[1], fmaf(sm[41], oh[2], sm[46]))) + h[r][1];
    float a2 = fmaf(sm[42], oh[0], fmaf(sm[43], oh[1], fmaf(sm[44], oh[2], sm[47]))) + h[r][2];
    ln3(a0, a1, a2, sm + 48, sm + 51);
    h[r][0] = a0; h[r][1] = a1; h[r][2] = a2;
    if (ckv) {
      float q0 = fmaf(sm[64], a0, fmaf(sm[65], a1, fmaf(sm[66], a2, sm[73])));
      float q1 = fmaf(sm[67], a0, fmaf(sm[68], a1, fmaf(sm[69], a2, sm[74])));
      float q2 = fmaf(sm[70], a0, fmaf(sm[71], a1, fmaf(sm[72], a2, sm[75])));
      qs[r][0] = q0; qs[r][1] = q1; qs[r][2] = q2;
    }
  }
  __syncthreads();
  if (ckv) {
    // Phase B2: cross-attn partials over 64 memory keys
    if (wave < 12 && lane < R) {
      const int hd = wave % 3, c = wave / 3;
      const int p0 = c * 16, p1 = p0 + 16;
      float q = qs[lane][hd] * 1.44269504f;
      float den = 0.f, num = 0.f;
      for (int p = p0; p < p1; ++p) {
        float e = exp2f(q * ckv[p][hd]);
        den += e;
        num = fmaf(e, ckv[p][3 + hd], num);
      }
      part[lane][wave * 2 + 0] = den;
      part[lane][wave * 2 + 1] = num;
    }
    __syncthreads();
    // Phase C2: combine cross, out-proj, residual, LN2
    if (wave == 0 && lane < R) {
      const int r = lane;
      float oh[3];
#pragma unroll
      for (int hd = 0; hd < 3; ++hd) {
        float den = part[r][hd * 2] + part[r][hd * 2 + 6] + part[r][hd * 2 + 12] + part[r][hd * 2 + 18];
        float num = part[r][hd * 2 + 1] + part[r][hd * 2 + 7] + part[r][hd * 2 + 13] + part[r][hd * 2 + 19];
        oh[hd] = __fdividef(num, den);
      }
      float a0 = fmaf(sm[76], oh[0], fmaf(sm[77], oh[1], fmaf(sm[78], oh[2], sm[85]))) + h[r][0];
      float a1 = fmaf(sm[79], oh[0], fmaf(sm[80], oh[1], fmaf(sm[81], oh[2], sm[86]))) + h[r][1];
      float a2 = fmaf(sm[82], oh[0], fmaf(sm[83], oh[1], fmaf(sm[84], oh[2], sm[87]))) + h[r][2];
      ln3(a0, a1, a2, sm + 54, sm + 57);
      h[r][0] = a0; h[r][1] = a1; h[r][2] = a2;
    }
    __syncthreads();
  }
  // FFN: each wave owns 4 rows; lanes split the 2048 hidden units (j = lane+64k)
  {
    const int r0 = wave * 4;
    if (r0 < R) {
      float xa[4], xb[4], xc[4];
#pragma unroll
      for (int i = 0; i < 4; ++i) {
        int r = min(r0 + i, R - 1);  // clamped dups are discarded below
        xa[i] = h[r][0]; xb[i] = h[r][1]; xc[i] = h[r][2];
      }
      float A0[4] = {0, 0, 0, 0}, A1[4] = {0, 0, 0, 0}, A2[4] = {0, 0, 0, 0};
      const float4* F = (const float4*)fw;
      const float4* S = (const float4*)sw;
      for (int kk = 0; kk < 32; ++kk) {
        int j = lane + (kk << 6);
        float4 a = F[j];
        float4 c = S[j];
#pragma unroll
        for (int i = 0; i < 4; ++i) {
          float tt = fmaf(a.x, xa[i], fmaf(a.y, xb[i], fmaf(a.z, xc[i], a.w)));
          tt = fmaxf(tt, 0.0f);
          A0[i] = fmaf(c.x, tt, A0[i]);
          A1[i] = fmaf(c.y, tt, A1[i]);
          A2[i] = fmaf(c.z, tt, A2[i]);
        }
      }
#pragma unroll
      for (int m = 1; m < 64; m <<= 1) {
#pragma unroll
        for (int i = 0; i < 4; ++i) {
          A0[i] += __shfl_xor(A0[i], m, 64);
          A1[i] += __shfl_xor(A1[i], m, 64);
          A2[i] += __shfl_xor(A2[i], m, 64);
        }
      }
      if (lane == 0) {
        const float* lng = ckv ? sm + 88 : sm + 54;
        const float* lnb = ckv ? sm + 91 : sm + 57;
        const int nr = min(4, R - r0);
        for (int i = 0; i < nr; ++i) {
          int r = r0 + i;
          float y0 = A0[i] + sm[60] + h[r][0];
          float y1 = A1[i] + sm[61] + h[r][1];
          float y2 = A2[i] + sm[62] + h[r][2];
          ln3(y0, y1, y2, lng, lnb);
          h[r][0] = y0; h[r][1] = y1; h[r][2] = y2;
        }
      }
    }
    __syncthreads();
  }
}

// ---------------------------------------------------------------------------
// Main kernel: one block per batch element b. Encoder -> cross K/V precompute
// -> 63 autoregressive decode steps with zero-row dedup -> output transpose.
// ---------------------------------------------------------------------------
__global__ void __launch_bounds__(1024) tf_kernel(const float* src, const float* angle,
                                                  const float* ws, float* out) {
  __shared__ float small_s[24][128];
  __shared__ float glob[16];
  __shared__ float h[64][5];
  __shared__ float qs[64][5];
  __shared__ float kvw[64][9];
  __shared__ float o_s[64][5];
  __shared__ float ckcv[12][64][8];
  __shared__ float part[64][25];
  __shared__ float xsave[3];
  const int b = blockIdx.x;
  const int tid = threadIdx.x, wave = tid >> 6, lane = tid & 63;
  const float* FW = ws;
  const float* SWp = ws + 24 * 8192;
  const float* SM = ws + 48 * 8192;
  const float* GB = SM + 24 * 128;
  for (int i = tid; i < 24 * 128; i += 1024) ((float*)small_s)[i] = SM[i];
  if (tid < 16) glob[tid] = GB[tid];
  if (tid < 64) {
    float x0 = src[b * 128 + tid];
    float x1 = src[b * 128 + 64 + tid];
    float x2 = angle[b];
    h[tid][0] = x0; h[tid][1] = x1; h[tid][2] = x2;
    o_s[tid][0] = 0.f; o_s[tid][1] = 0.f; o_s[tid][2] = 0.f;
  }
  __syncthreads();
  if (tid == 0) { xsave[0] = h[0][0]; xsave[1] = h[0][1]; xsave[2] = h[0][2]; }
  // ---- encoder (64 distinct rows) ----
  for (int l = 0; l < 12; ++l)
    run_layer(small_s[l], FW + l * 8192, SWp + l * 8192, h, qs, kvw, part,
              (const float(*)[8]) nullptr, wave, lane, 64, 0);
  // final encoder LN -> mem (in place in h)
  if (tid < 64) {
    float a = h[tid][0], bb = h[tid][1], c = h[tid][2];
    ln3(a, bb, c, glob + 0, glob + 3);
    h[tid][0] = a; h[tid][1] = bb; h[tid][2] = c;
  }
  __syncthreads();
  // ---- precompute cross-attn K/V per decoder layer (mem is fixed) ----
  if (wave < 12) {
    const float* sm = small_s[12 + wave];
    float m0 = h[lane][0], m1 = h[lane][1], m2 = h[lane][2];
    float k0 = fmaf(sm[94], m0, fmaf(sm[95], m1, fmaf(sm[96], m2, sm[103])));
    float k1 = fmaf(sm[97], m0, fmaf(sm[98], m1, fmaf(sm[99], m2, sm[104])));
    float k2 = fmaf(sm[100], m0, fmaf(sm[101], m1, fmaf(sm[102], m2, sm[105])));
    float v0 = fmaf(sm[106], m0, fmaf(sm[107], m1, fmaf(sm[108], m2, sm[115])));
    float v1 = fmaf(sm[109], m0, fmaf(sm[110], m1, fmaf(sm[111], m2, sm[116])));
    float v2 = fmaf(sm[112], m0, fmaf(sm[113], m1, fmaf(sm[114], m2, sm[117])));
    ckcv[wave][lane][0] = k0; ckcv[wave][lane][1] = k1; ckcv[wave][lane][2] = k2;
    ckcv[wave][lane][3] = v0; ckcv[wave][lane][4] = v1; ckcv[wave][lane][5] = v2;
  }
  __syncthreads();
  if (tid == 0) { o_s[0][0] = xsave[0]; o_s[0][1] = xsave[1]; o_s[0][2] = xsave[2]; }
  __syncthreads();
  // ---- autoregressive decode: step t fills position t ----
  for (int t = 1; t < 64; ++t) {
    const int R = t + 1;  // t filled rows + 1 zero-representative (mult 64-t)
    if (tid < R) {
      if (tid < t) {
        h[tid][0] = o_s[tid][0]; h[tid][1] = o_s[tid][1]; h[tid][2] = o_s[tid][2];
      } else {
        h[tid][0] = 0.f; h[tid][1] = 0.f; h[tid][2] = 0.f;
      }
    }
    __syncthreads();
    for (int l = 0; l < 12; ++l)
      run_layer(small_s[12 + l], FW + (12 + l) * 8192, SWp + (12 + l) * 8192,
                h, qs, kvw, part, ckcv[l], wave, lane, R, t);
    if (tid == 0) {
      float a = h[R - 1][0], bb = h[R - 1][1], c = h[R - 1][2];  // zero-row rep = pred[t]
      ln3(a, bb, c, glob + 6, glob + 9);
      o_s[t][0] = a; o_s[t][1] = bb; o_s[t][2] = c;
    }
    __syncthreads();
  }
  // ---- output: [B,3,T] = transpose(out,(1,2,0)) ----
  if (tid < 192) {
    int d = tid / 64, tt = tid % 64;
    out[b * 192 + tid] = o_s[tt][d];
  }
}

extern "C" void kernel_launch(void* const* d_in, const int* in_sizes, int n_in,
                              void* d_out, int out_size, void* d_ws, size_t ws_size,
                              hipStream_t stream) {
  (void)in_sizes; (void)n_in; (void)out_size; (void)ws_size;
  float* ws = (float*)d_ws;
  prepack_kernel<<<24, 256, 0, stream>>>(
      (const float*)d_in[2], (const float*)d_in[3], (const float*)d_in[4], (const float*)d_in[5],
      (const float*)d_in[6], (const float*)d_in[7], (const float*)d_in[8], (const float*)d_in[9],
      (const float*)d_in[10], (const float*)d_in[11], (const float*)d_in[12], (const float*)d_in[13],
      (const float*)d_in[14], (const float*)d_in[15],
      (const float*)d_in[16], (const float*)d_in[17], (const float*)d_in[18], (const float*)d_in[19],
      (const float*)d_in[20], (const float*)d_in[21], (const float*)d_in[22], (const float*)d_in[23],
      (const float*)d_in[24], (const float*)d_in[25], (const float*)d_in[26], (const float*)d_in[27],
      (const float*)d_in[28], (const float*)d_in[29],
      (const float*)d_in[30], (const float*)d_in[31], (const float*)d_in[32], (const float*)d_in[33],
      (const float*)d_in[34], (const float*)d_in[35],
      ws);
  tf_kernel<<<32, 1024, 0, stream>>>((const float*)d_in[0], (const float*)d_in[1], ws,
                                     (float*)d_out);
}